// Round 2
// baseline (845.782 us; speedup 1.0000x reference)
//
#include <hip/hip_runtime.h>

// CrossChannelAttention on MI355X (gfx950).
// B=4, C=192, H=W=192, HW=36864, heads=6, d=32.
// Pipeline: detect dtype -> convert/transpose -> kv 1x1 GEMM -> depthwise 3x3
//        -> q 3x3 implicit GEMM -> gram [q;k][q;k]^T (norms from diagonal)
//        -> softmax + fused (proj @ blockdiag(attn)) -> final GEMM.
// All GEMMs: v_mfma_f32_16x16x32_bf16, f32 accumulate, bf16 intermediates.

#define DEV static __device__ __forceinline__

typedef __attribute__((ext_vector_type(8))) unsigned short U16x8;
typedef __attribute__((ext_vector_type(4))) unsigned short U16x4;
typedef __attribute__((ext_vector_type(8))) __bf16 BF16x8;
typedef __attribute__((ext_vector_type(4))) float F32x4;

DEV unsigned short f2bf(float f) {
  unsigned u = __float_as_uint(f);
  u += 0x7FFFu + ((u >> 16) & 1u);   // round-to-nearest-even
  return (unsigned short)(u >> 16);
}
DEV float bf2f(unsigned short h) { return __uint_as_float(((unsigned)h) << 16); }

#define NB 4
#define NC 192
#define NHW 36864          // 192*192
#define IMG 7077888        // 192*36864 elements per batch (CHW or HWC)

// ---------------------------------------------------------------- detect dtype
// temperature = ones(6): bf16 pair -> 0x3F803F80, f32 -> 0x3F800000.
__global__ void k_detect(const void* temp_in, int* flag, float* temp6) {
  if (threadIdx.x == 0) {
    unsigned bits = *(const unsigned*)temp_in;
    int isbf = ((bits & 0xFFFFu) == 0x3F80u) ? 1 : 0;
    *flag = isbf;
    for (int h = 0; h < 6; ++h) {
      float t = isbf ? bf2f(((const unsigned short*)temp_in)[h])
                     : ((const float*)temp_in)[h];
      temp6[h] = t;
    }
  }
}

// ---------------------------------------------------------------- weight prep
// wt9[tap][oc][ic] (k-contig), kvwt[oc][ic], pjwt[oc][ic], dwt[tap][c] (f32)
__global__ void k_prep(const void* qw, const void* kvw, const void* pjw, const void* dww,
                       const int* flagp, unsigned short* wt9, unsigned short* kvwt,
                       unsigned short* pjwt, float* dwt) {
  int flag = *flagp;
  for (int i = blockIdx.x * 256 + threadIdx.x; i < 445824; i += gridDim.x * 256) {
    if (i < 331776) {                       // q_w: [oc][ic][tap] -> [tap][oc*192+ic]
      int tap = i / 36864, r = i - tap * 36864;
      int src = r * 9 + tap;
      float v = flag ? bf2f(((const unsigned short*)qw)[src]) : ((const float*)qw)[src];
      wt9[i] = f2bf(v);
    } else if (i < 405504) {                // kv_w: straight copy [384][192]
      int j = i - 331776;
      float v = flag ? bf2f(((const unsigned short*)kvw)[j]) : ((const float*)kvw)[j];
      kvwt[j] = f2bf(v);
    } else if (i < 442368) {                // proj_w: [192][192]
      int j = i - 405504;
      float v = flag ? bf2f(((const unsigned short*)pjw)[j]) : ((const float*)pjw)[j];
      pjwt[j] = f2bf(v);
    } else {                                // kvdw_w: [c][tap] -> dwt[tap][c] f32
      int j = i - 442368;
      int c = j / 9, tap = j - c * 9;
      float v = flag ? bf2f(((const unsigned short*)dww)[j]) : ((const float*)dww)[j];
      dwt[tap * 384 + c] = v;
    }
  }
}

// ------------------------------------------------- NCHW -> NHWC bf16 transpose
// grid: (576 ntiles, 24 = b*6+ctile, 2 = which tensor). tile 32c x 64n.
__global__ __launch_bounds__(256) void k_transpose(const void* xin, const void* yin,
                                                   const int* flagp,
                                                   unsigned short* xt, unsigned short* yt) {
  __shared__ unsigned short tile[32][65];
  int flag = *flagp;
  const void* src = blockIdx.z ? yin : xin;
  unsigned short* dst = blockIdx.z ? yt : xt;
  int n0 = blockIdx.x * 64;
  int b = blockIdx.y / 6, c0 = (blockIdx.y % 6) * 32;
  size_t base_in = (size_t)b * IMG;
  int tid = threadIdx.x;
  int nl = tid & 63, cl0 = tid >> 6;
  for (int i = 0; i < 8; ++i) {
    int cl = cl0 + i * 4;
    size_t idx = base_in + (size_t)(c0 + cl) * NHW + n0 + nl;
    unsigned short v = flag ? ((const unsigned short*)src)[idx]
                            : f2bf(((const float*)src)[idx]);
    tile[cl][nl] = v;
  }
  __syncthreads();
  int nl2 = tid >> 2, co = (tid & 3) * 8;
  U16x8 v;
  #pragma unroll
  for (int j = 0; j < 8; ++j) v[j] = tile[co + j][nl2];
  *(U16x8*)(dst + (size_t)b * IMG + (size_t)(n0 + nl2) * NC + c0 + co) = v;
}

// --------------------------------------------------------- K1: kv = 1x1 conv
// kv0_nhwc[b][n][oc] = sum_ic kvwt[oc][ic] * yt[b][n][ic]
// rows = oc (192-tile), cols = n (64-tile). grid (576, 2, 4).
__global__ __launch_bounds__(256) void k_conv1x1(const unsigned short* yt,
                                                 const unsigned short* kvwt,
                                                 unsigned short* kv0) {
  __shared__ unsigned short As[192 * 40];   // weights [oc][k]
  __shared__ unsigned short Bs[64 * 40];    // activ   [n][k]
  int b = blockIdx.z, octile = blockIdx.y, n0 = blockIdx.x * 64;
  const unsigned short* ybase = yt + (size_t)b * IMG;
  int tid = threadIdx.x, wave = tid >> 6, lane = tid & 63;
  int quad = lane >> 4, m = lane & 15;
  F32x4 acc[3][4] = {};
  for (int kc = 0; kc < 6; ++kc) {
    int k0 = kc * 32;
    for (int u = tid; u < 768; u += 256) {
      int row = u >> 2, oct = u & 3;
      U16x8 v = *(const U16x8*)(kvwt + (size_t)(octile * 192 + row) * 192 + k0 + oct * 8);
      *(U16x8*)(As + row * 40 + oct * 8) = v;
    }
    {
      int row = tid >> 2, oct = tid & 3;
      U16x8 v = *(const U16x8*)(ybase + (size_t)(n0 + row) * NC + k0 + oct * 8);
      *(U16x8*)(Bs + row * 40 + oct * 8) = v;
    }
    __syncthreads();
    BF16x8 bfr[4];
    #pragma unroll
    for (int cf = 0; cf < 4; ++cf)
      bfr[cf] = *(const BF16x8*)(Bs + (cf * 16 + m) * 40 + quad * 8);
    #pragma unroll
    for (int rf = 0; rf < 3; ++rf) {
      BF16x8 afr = *(const BF16x8*)(As + (wave * 48 + rf * 16 + m) * 40 + quad * 8);
      #pragma unroll
      for (int cf = 0; cf < 4; ++cf)
        acc[rf][cf] = __builtin_amdgcn_mfma_f32_16x16x32_bf16(afr, bfr[cf], acc[rf][cf], 0, 0, 0);
    }
    __syncthreads();
  }
  #pragma unroll
  for (int rf = 0; rf < 3; ++rf)
    #pragma unroll
    for (int cf = 0; cf < 4; ++cf) {
      int nl = cf * 16 + m;
      int oc = octile * 192 + wave * 48 + rf * 16 + quad * 4;
      U16x4 s;
      #pragma unroll
      for (int r = 0; r < 4; ++r) s[r] = f2bf(acc[rf][cf][r]);
      *(U16x4*)(kv0 + (size_t)b * 14155776 + (size_t)(n0 + nl) * 384 + oc) = s;
    }
}

// ------------------------------------------------ K2: depthwise 3x3 + split
// k -> NCHW (via LDS transpose), v -> NHWC. grid (576 = h*3+wtile, 4 cgrp, 4 b)
__global__ __launch_bounds__(256) void k_dw(const unsigned short* kv0, const float* dwt,
                                            unsigned short* knchw, unsigned short* vnhwc) {
  __shared__ unsigned short lt[96 * 72];
  int b = blockIdx.z, cg = blockIdx.y, t = blockIdx.x;
  int h = t / 3, w0 = (t % 3) * 64;
  int c0 = cg * 96;
  const unsigned short* kb = kv0 + (size_t)b * 14155776;
  int tid = threadIdx.x;
  for (int u = tid; u < 768; u += 256) {
    int wl = u / 12, cv = u - wl * 12;
    int cc = c0 + cv * 8;
    float r[8] = {0.f, 0.f, 0.f, 0.f, 0.f, 0.f, 0.f, 0.f};
    for (int dy = 0; dy < 3; ++dy) {
      int sr = h + dy - 1;
      if (sr < 0 || sr >= 192) continue;
      for (int dx = 0; dx < 3; ++dx) {
        int sw = w0 + wl + dx - 1;
        if (sw < 0 || sw >= 192) continue;
        int tap = dy * 3 + dx;
        U16x8 v = *(const U16x8*)(kb + (size_t)(sr * 192 + sw) * 384 + cc);
        const float* dptr = dwt + tap * 384 + cc;
        #pragma unroll
        for (int j = 0; j < 8; ++j) r[j] += bf2f(v[j]) * dptr[j];
      }
    }
    if (cg < 2) {
      #pragma unroll
      for (int j = 0; j < 8; ++j) lt[(cv * 8 + j) * 72 + wl] = f2bf(r[j]);
    } else {
      U16x8 s;
      #pragma unroll
      for (int j = 0; j < 8; ++j) s[j] = f2bf(r[j]);
      *(U16x8*)(vnhwc + (size_t)b * IMG + (size_t)(h * 192 + w0 + wl) * NC + (cc - 192)) = s;
    }
  }
  if (cg < 2) {
    __syncthreads();
    for (int u = tid; u < 768; u += 256) {
      int cl = u >> 3, wo = u & 7;
      U16x8 s = *(const U16x8*)(lt + cl * 72 + wo * 8);
      *(U16x8*)(knchw + (size_t)b * IMG + (size_t)(c0 + cl) * NHW + h * 192 + w0 + wo * 8) = s;
    }
  }
}

// ----------------------------------------------- K3: q = 3x3 conv (implicit GEMM)
// rows = n (128-tile), cols = oc (192). K = 9 taps x 192 ic. Output q NCHW.
// grid (288, 4)
__global__ __launch_bounds__(256) void k_conv3x3(const unsigned short* xt,
                                                 const unsigned short* wt9,
                                                 unsigned short* q) {
  __shared__ unsigned short As[128 * 40];   // activations [n][k]
  __shared__ unsigned short Bs[192 * 40];   // weights     [oc][k]
  int b = blockIdx.y, nt = blockIdx.x;
  int n0 = nt * 128;
  const unsigned short* xb = xt + (size_t)b * IMG;
  int tid = threadIdx.x, wave = tid >> 6, lane = tid & 63;
  int quad = lane >> 4, m = lane & 15;
  F32x4 acc[8][3] = {};
  for (int tap = 0; tap < 9; ++tap) {
    int dy = tap / 3, dx = tap - dy * 3;
    for (int kc = 0; kc < 6; ++kc) {
      int k0 = kc * 32;
      for (int u = tid; u < 512; u += 256) {          // A: 128 rows x 4 octs
        int rl = u >> 2, oct = u & 3;
        int n = n0 + rl;
        int hh = n / 192, wr = n - hh * 192;
        int sr = hh + dy - 1, sw = wr + dx - 1;
        U16x8 v = {};
        if (sr >= 0 && sr < 192 && sw >= 0 && sw < 192)
          v = *(const U16x8*)(xb + (size_t)(sr * 192 + sw) * NC + k0 + oct * 8);
        *(U16x8*)(As + rl * 40 + oct * 8) = v;
      }
      for (int u = tid; u < 768; u += 256) {          // B: 192 oc x 4 octs
        int row = u >> 2, oct = u & 3;
        U16x8 v = *(const U16x8*)(wt9 + (size_t)tap * 36864 + row * 192 + k0 + oct * 8);
        *(U16x8*)(Bs + row * 40 + oct * 8) = v;
      }
      __syncthreads();
      BF16x8 afr[8];
      #pragma unroll
      for (int rf = 0; rf < 8; ++rf)
        afr[rf] = *(const BF16x8*)(As + (rf * 16 + m) * 40 + quad * 8);
      #pragma unroll
      for (int cf = 0; cf < 3; ++cf) {
        BF16x8 bfr = *(const BF16x8*)(Bs + (wave * 48 + cf * 16 + m) * 40 + quad * 8);
        #pragma unroll
        for (int rf = 0; rf < 8; ++rf)
          acc[rf][cf] = __builtin_amdgcn_mfma_f32_16x16x32_bf16(afr[rf], bfr, acc[rf][cf], 0, 0, 0);
      }
      __syncthreads();
    }
  }
  size_t qb = (size_t)b * IMG;
  #pragma unroll
  for (int rf = 0; rf < 8; ++rf)
    #pragma unroll
    for (int cf = 0; cf < 3; ++cf) {
      int oc = wave * 48 + cf * 16 + m;
      int nl = rf * 16 + quad * 4;
      U16x4 s;
      #pragma unroll
      for (int r = 0; r < 4; ++r) s[r] = f2bf(acc[rf][cf][r]);
      *(U16x4*)(q + qb + (size_t)oc * NHW + n0 + nl) = s;
    }
}

// --------------------------------------- K4a: G = [q;k][q;k]^T per (b, head)
// G[64][64] f32; diag = squared L2 norms, block (0:32,32:64) = q.k^T.
// grid (32 splits, 6 heads, 4 b); atomicAdd partials.
__global__ __launch_bounds__(256) void k_gram(const unsigned short* q,
                                              const unsigned short* k, float* G) {
  __shared__ unsigned short Zs[64 * 72];
  int b = blockIdx.z, h = blockIdx.y, sp = blockIdx.x;
  const unsigned short* qb = q + (size_t)b * IMG + (size_t)h * 32 * NHW;
  const unsigned short* kb = k + (size_t)b * IMG + (size_t)h * 32 * NHW;
  int tid = threadIdx.x, wave = tid >> 6, lane = tid & 63;
  int quad = lane >> 4, m = lane & 15;
  F32x4 acc[4] = {};
  for (int it = 0; it < 18; ++it) {
    int nb = sp * 1152 + it * 64;
    for (int u = tid; u < 512; u += 256) {
      int row = u >> 3, oct = u & 7;
      const unsigned short* src = (row < 32) ? (qb + (size_t)row * NHW)
                                             : (kb + (size_t)(row - 32) * NHW);
      U16x8 v = *(const U16x8*)(src + nb + oct * 8);
      *(U16x8*)(Zs + row * 72 + oct * 8) = v;
    }
    __syncthreads();
    #pragma unroll
    for (int ks = 0; ks < 2; ++ks) {
      BF16x8 afr = *(const BF16x8*)(Zs + (wave * 16 + m) * 72 + ks * 32 + quad * 8);
      #pragma unroll
      for (int cg = 0; cg < 4; ++cg) {
        BF16x8 bfr = *(const BF16x8*)(Zs + (cg * 16 + m) * 72 + ks * 32 + quad * 8);
        acc[cg] = __builtin_amdgcn_mfma_f32_16x16x32_bf16(afr, bfr, acc[cg], 0, 0, 0);
      }
    }
    __syncthreads();
  }
  float* Gb = G + (size_t)(b * 6 + h) * 4096;
  #pragma unroll
  for (int cg = 0; cg < 4; ++cg) {
    int s = cg * 16 + m;
    #pragma unroll
    for (int r = 0; r < 4; ++r) {
      int row = wave * 16 + quad * 4 + r;
      atomicAdd(Gb + row * 64 + s, acc[cg][r]);
    }
  }
}

// ------------------- K4b: softmax + M_b = proj_w @ blockdiag(attn). grid(24)
__global__ __launch_bounds__(256) void k_attn(const float* G, const float* temp6,
                                              const unsigned short* pjw,
                                              unsigned short* M) {
  __shared__ float attn[32][33];
  int bh = blockIdx.x;
  int b = bh / 6, h = bh - b * 6;
  const float* Gb = G + (size_t)bh * 4096;
  int tid = threadIdx.x;
  float temp = temp6[h];
  if (tid < 32) {
    int c = tid;
    float qn = sqrtf(fmaxf(Gb[c * 64 + c], 0.f));
    qn = fmaxf(qn, 1e-12f);
    float s[32];
    float mx = -1e30f;
    for (int d = 0; d < 32; ++d) {
      float kn = sqrtf(fmaxf(Gb[(32 + d) * 64 + 32 + d], 0.f));
      kn = fmaxf(kn, 1e-12f);
      float v = Gb[c * 64 + 32 + d] / (qn * kn) * temp;
      s[d] = v;
      mx = fmaxf(mx, v);
    }
    float sum = 0.f;
    for (int d = 0; d < 32; ++d) { float e = __expf(s[d] - mx); s[d] = e; sum += e; }
    float inv = 1.f / sum;
    for (int d = 0; d < 32; ++d) attn[c][d] = s[d] * inv;
  }
  __syncthreads();
  // M[b][oc][h*32+d] = sum_c pjw[oc][h*32+c] * attn[c][d]
  for (int u = tid; u < 6144; u += 256) {
    int oc = u >> 5, d = u & 31;
    float sum = 0.f;
    #pragma unroll
    for (int c = 0; c < 32; ++c)
      sum += bf2f(pjw[oc * 192 + h * 32 + c]) * attn[c][d];
    M[(size_t)b * 36864 + oc * 192 + h * 32 + d] = f2bf(sum);
  }
}

// ------------------------------- K5: out = M_b @ v (fused attn@v + proj 1x1)
// rows = n (64-tile), cols = oc (192). grid (576, 4). Store per dtype flag.
__global__ __launch_bounds__(256) void k_out(const unsigned short* v,
                                             const unsigned short* M,
                                             const int* flagp, void* out) {
  __shared__ unsigned short As[64 * 40];
  __shared__ unsigned short Bs[192 * 40];
  int b = blockIdx.y, nt = blockIdx.x;
  int n0 = nt * 64;
  const unsigned short* vb = v + (size_t)b * IMG;
  const unsigned short* Mb = M + (size_t)b * 36864;
  int tid = threadIdx.x, wave = tid >> 6, lane = tid & 63;
  int quad = lane >> 4, m = lane & 15;
  F32x4 acc[4][3] = {};
  for (int kc = 0; kc < 6; ++kc) {
    int k0 = kc * 32;
    {
      int rl = tid >> 2, oct = tid & 3;
      U16x8 vv = *(const U16x8*)(vb + (size_t)(n0 + rl) * NC + k0 + oct * 8);
      *(U16x8*)(As + rl * 40 + oct * 8) = vv;
    }
    for (int u = tid; u < 768; u += 256) {
      int row = u >> 2, oct = u & 3;
      U16x8 vv = *(const U16x8*)(Mb + row * 192 + k0 + oct * 8);
      *(U16x8*)(Bs + row * 40 + oct * 8) = vv;
    }
    __syncthreads();
    BF16x8 afr[4];
    #pragma unroll
    for (int rf = 0; rf < 4; ++rf)
      afr[rf] = *(const BF16x8*)(As + (rf * 16 + m) * 40 + quad * 8);
    #pragma unroll
    for (int cf = 0; cf < 3; ++cf) {
      BF16x8 bfr = *(const BF16x8*)(Bs + (wave * 48 + cf * 16 + m) * 40 + quad * 8);
      #pragma unroll
      for (int rf = 0; rf < 4; ++rf)
        acc[rf][cf] = __builtin_amdgcn_mfma_f32_16x16x32_bf16(afr[rf], bfr, acc[rf][cf], 0, 0, 0);
    }
    __syncthreads();
  }
  int flag = *flagp;
  #pragma unroll
  for (int rf = 0; rf < 4; ++rf)
    #pragma unroll
    for (int cf = 0; cf < 3; ++cf) {
      int oc = wave * 48 + cf * 16 + m;
      int nl = rf * 16 + quad * 4;
      size_t off = (size_t)b * IMG + (size_t)oc * NHW + n0 + nl;
      if (flag) {
        U16x4 s;
        #pragma unroll
        for (int r = 0; r < 4; ++r) s[r] = f2bf(acc[rf][cf][r]);
        *(U16x4*)((unsigned short*)out + off) = s;
      } else {
        F32x4 s;
        #pragma unroll
        for (int r = 0; r < 4; ++r) s[r] = acc[rf][cf][r];
        *(F32x4*)((float*)out + off) = s;
      }
    }
}

extern "C" void kernel_launch(void* const* d_in, const int* in_sizes, int n_in,
                              void* d_out, int out_size, void* d_ws, size_t ws_size,
                              hipStream_t stream) {
  (void)in_sizes; (void)n_in; (void)out_size; (void)ws_size;
  char* p = (char*)d_ws;
  int*            flag  = (int*)p;
  float*          temp6 = (float*)(p + 16);
  unsigned short* wt9   = (unsigned short*)(p + 256);        //   663,552 B
  unsigned short* kvwt  = (unsigned short*)(p + 663808);     //   147,456 B
  float*          dwt   = (float*)(p + 811264);              //    13,824 B
  unsigned short* pjwt  = (unsigned short*)(p + 825088);     //    73,728 B
  unsigned short* xt    = (unsigned short*)(p + 1048576);    // 56,623,104 B (x NHWC)
  unsigned short* yt    = (unsigned short*)(p + 57671680);   // 56,623,104 B (y NHWC; reused as k NCHW)
  unsigned short* kv0   = (unsigned short*)(p + 114294784);  // 113,246,208 B (kv0 NHWC; reused as q NCHW)
  unsigned short* vv    = (unsigned short*)(p + 227540992);  // 56,623,104 B (v NHWC)
  float*          G     = (float*)(p + 284164096);           //   393,216 B
  unsigned short* M     = (unsigned short*)(p + 284557312);  //   294,912 B
  unsigned short* kq    = yt;   // k NCHW aliases y_t (dead after k_conv1x1)
  unsigned short* q     = kv0;  // q NCHW aliases kv0 (dead after k_dw)

  hipMemsetAsync(G, 0, (size_t)24 * 4096 * 4, stream);
  k_detect<<<1, 64, 0, stream>>>(d_in[6], flag, temp6);
  k_prep<<<512, 256, 0, stream>>>(d_in[2], d_in[3], d_in[5], d_in[4],
                                  flag, wt9, kvwt, pjwt, dwt);
  k_transpose<<<dim3(576, 24, 2), 256, 0, stream>>>(d_in[0], d_in[1], flag, xt, yt);
  k_conv1x1<<<dim3(576, 2, 4), 256, 0, stream>>>(yt, kvwt, kv0);
  k_dw<<<dim3(576, 4, 4), 256, 0, stream>>>(kv0, dwt, kq, vv);
  k_conv3x3<<<dim3(288, 4), 256, 0, stream>>>(xt, wt9, q);
  k_gram<<<dim3(32, 6, 4), 256, 0, stream>>>(q, kq, G);
  k_attn<<<24, 256, 0, stream>>>(G, temp6, pjwt, M);
  k_out<<<dim3(576, 4), 256, 0, stream>>>(vv, M, flag, d_out);
}

// Round 3
// 729.921 us; speedup vs baseline: 1.1587x; 1.1587x over previous
//
#include <hip/hip_runtime.h>

// CrossChannelAttention on MI355X (gfx950).
// B=4, C=192, H=W=192, HW=36864, heads=6, d=32.
// R3: k_conv3x3 rebuilt m97-style: spatially padded x (194x194, zero halo),
//     global_load_lds width=16 staging (no VGPR roundtrip, no predicates),
//     BK=64 (27 chunks x 48 MFMA), XOR-swizzled LDS (pad-free, conflict-free).

#define DEV static __device__ __forceinline__

typedef __attribute__((ext_vector_type(8))) unsigned short U16x8;
typedef __attribute__((ext_vector_type(4))) unsigned short U16x4;
typedef __attribute__((ext_vector_type(8))) __bf16 BF16x8;
typedef __attribute__((ext_vector_type(4))) float F32x4;

DEV unsigned short f2bf(float f) {
  unsigned u = __float_as_uint(f);
  u += 0x7FFFu + ((u >> 16) & 1u);   // round-to-nearest-even
  return (unsigned short)(u >> 16);
}
DEV float bf2f(unsigned short h) { return __uint_as_float(((unsigned)h) << 16); }

DEV void gl2lds16(const unsigned short* g, void* l) {
  __builtin_amdgcn_global_load_lds(
      (const __attribute__((address_space(1))) unsigned int*)g,
      (__attribute__((address_space(3))) unsigned int*)l, 16, 0, 0);
}

#define NC 192
#define NHW 36864          // 192*192
#define IMG 7077888        // 192*36864 elements per batch
#define PP 194             // padded pitch
#define PIMG 7226112       // 194*194*192 elements per batch

// ---------------------------------------------------------------- detect dtype
__global__ void k_detect(const void* temp_in, int* flag, float* temp6) {
  if (threadIdx.x == 0) {
    unsigned bits = *(const unsigned*)temp_in;
    int isbf = ((bits & 0xFFFFu) == 0x3F80u) ? 1 : 0;
    *flag = isbf;
    for (int h = 0; h < 6; ++h) {
      float t = isbf ? bf2f(((const unsigned short*)temp_in)[h])
                     : ((const float*)temp_in)[h];
      temp6[h] = t;
    }
  }
}

// ---------------------------------------------------------------- weight prep
__global__ void k_prep(const void* qw, const void* kvw, const void* pjw, const void* dww,
                       const int* flagp, unsigned short* wt9, unsigned short* kvwt,
                       unsigned short* pjwt, float* dwt) {
  int flag = *flagp;
  for (int i = blockIdx.x * 256 + threadIdx.x; i < 445824; i += gridDim.x * 256) {
    if (i < 331776) {                       // q_w: [oc][ic][tap] -> [tap][oc*192+ic]
      int tap = i / 36864, r = i - tap * 36864;
      int src = r * 9 + tap;
      float v = flag ? bf2f(((const unsigned short*)qw)[src]) : ((const float*)qw)[src];
      wt9[i] = f2bf(v);
    } else if (i < 405504) {                // kv_w [384][192]
      int j = i - 331776;
      float v = flag ? bf2f(((const unsigned short*)kvw)[j]) : ((const float*)kvw)[j];
      kvwt[j] = f2bf(v);
    } else if (i < 442368) {                // proj_w [192][192]
      int j = i - 405504;
      float v = flag ? bf2f(((const unsigned short*)pjw)[j]) : ((const float*)pjw)[j];
      pjwt[j] = f2bf(v);
    } else {                                // kvdw_w: [c][tap] -> dwt[tap][c]
      int j = i - 442368;
      int c = j / 9, tap = j - c * 9;
      float v = flag ? bf2f(((const unsigned short*)dww)[j]) : ((const float*)dww)[j];
      dwt[tap * 384 + c] = v;
    }
  }
}

// ----------------------------------------------------- zero halo of padded x
__global__ void k_halo(unsigned short* xpad) {
  unsigned short* p = xpad + (size_t)blockIdx.x * PIMG;
  U16x8 z = {};
  for (int i = threadIdx.x; i < 4656; i += 256) {        // ph=0 and ph=193 rows
    *(U16x8*)(p + i * 8) = z;
    *(U16x8*)(p + (size_t)193 * PP * 192 + i * 8) = z;
  }
  for (int u = threadIdx.x; u < 4608; u += 256) {        // pw=0/193 cols, ph 1..192
    int ph = 1 + u / 24, vj = u % 24;
    *(U16x8*)(p + ((size_t)ph * PP) * 192 + vj * 8) = z;
    *(U16x8*)(p + ((size_t)ph * PP + 193) * 192 + vj * 8) = z;
  }
}

// ------------------------------------------------- NCHW -> NHWC bf16 transpose
// x goes into padded interior (ph=h+1, pw=w+1); y into plain NHWC.
__global__ __launch_bounds__(256) void k_transpose(const void* xin, const void* yin,
                                                   const int* flagp,
                                                   unsigned short* xpad, unsigned short* yt) {
  __shared__ unsigned short tile[32][65];
  int flag = *flagp;
  const void* src = blockIdx.z ? yin : xin;
  int n0 = blockIdx.x * 64;
  int b = blockIdx.y / 6, c0 = (blockIdx.y % 6) * 32;
  size_t base_in = (size_t)b * IMG;
  int tid = threadIdx.x;
  int nl = tid & 63, cl0 = tid >> 6;
  for (int i = 0; i < 8; ++i) {
    int cl = cl0 + i * 4;
    size_t idx = base_in + (size_t)(c0 + cl) * NHW + n0 + nl;
    unsigned short v = flag ? ((const unsigned short*)src)[idx]
                            : f2bf(((const float*)src)[idx]);
    tile[cl][nl] = v;
  }
  __syncthreads();
  int nl2 = tid >> 2, co = (tid & 3) * 8;
  U16x8 v;
  #pragma unroll
  for (int j = 0; j < 8; ++j) v[j] = tile[co + j][nl2];
  int n = n0 + nl2;
  if (blockIdx.z == 0) {
    int hh = n / 192, ww = n - hh * 192;
    *(U16x8*)(xpad + (size_t)b * PIMG + ((size_t)(hh + 1) * PP + (ww + 1)) * 192 + c0 + co) = v;
  } else {
    *(U16x8*)(yt + (size_t)b * IMG + (size_t)n * NC + c0 + co) = v;
  }
}

// --------------------------------------------------------- K1: kv = 1x1 conv
__global__ __launch_bounds__(256) void k_conv1x1(const unsigned short* yt,
                                                 const unsigned short* kvwt,
                                                 unsigned short* kv0) {
  __shared__ unsigned short As[192 * 40];   // weights [oc][k]
  __shared__ unsigned short Bs[64 * 40];    // activ   [n][k]
  int b = blockIdx.z, octile = blockIdx.y, n0 = blockIdx.x * 64;
  const unsigned short* ybase = yt + (size_t)b * IMG;
  int tid = threadIdx.x, wave = tid >> 6, lane = tid & 63;
  int quad = lane >> 4, m = lane & 15;
  F32x4 acc[3][4] = {};
  for (int kc = 0; kc < 6; ++kc) {
    int k0 = kc * 32;
    for (int u = tid; u < 768; u += 256) {
      int row = u >> 2, oct = u & 3;
      U16x8 v = *(const U16x8*)(kvwt + (size_t)(octile * 192 + row) * 192 + k0 + oct * 8);
      *(U16x8*)(As + row * 40 + oct * 8) = v;
    }
    {
      int row = tid >> 2, oct = tid & 3;
      U16x8 v = *(const U16x8*)(ybase + (size_t)(n0 + row) * NC + k0 + oct * 8);
      *(U16x8*)(Bs + row * 40 + oct * 8) = v;
    }
    __syncthreads();
    BF16x8 bfr[4];
    #pragma unroll
    for (int cf = 0; cf < 4; ++cf)
      bfr[cf] = *(const BF16x8*)(Bs + (cf * 16 + m) * 40 + quad * 8);
    #pragma unroll
    for (int rf = 0; rf < 3; ++rf) {
      BF16x8 afr = *(const BF16x8*)(As + (wave * 48 + rf * 16 + m) * 40 + quad * 8);
      #pragma unroll
      for (int cf = 0; cf < 4; ++cf)
        acc[rf][cf] = __builtin_amdgcn_mfma_f32_16x16x32_bf16(afr, bfr[cf], acc[rf][cf], 0, 0, 0);
    }
    __syncthreads();
  }
  #pragma unroll
  for (int rf = 0; rf < 3; ++rf)
    #pragma unroll
    for (int cf = 0; cf < 4; ++cf) {
      int nl = cf * 16 + m;
      int oc = octile * 192 + wave * 48 + rf * 16 + quad * 4;
      U16x4 s;
      #pragma unroll
      for (int r = 0; r < 4; ++r) s[r] = f2bf(acc[rf][cf][r]);
      *(U16x4*)(kv0 + (size_t)b * 14155776 + (size_t)(n0 + nl) * 384 + oc) = s;
    }
}

// ------------------------------------------------ K2: depthwise 3x3 + split
__global__ __launch_bounds__(256) void k_dw(const unsigned short* kv0, const float* dwt,
                                            unsigned short* knchw, unsigned short* vnhwc) {
  __shared__ unsigned short lt[96 * 72];
  int b = blockIdx.z, cg = blockIdx.y, t = blockIdx.x;
  int h = t / 3, w0 = (t % 3) * 64;
  int c0 = cg * 96;
  const unsigned short* kb = kv0 + (size_t)b * 14155776;
  int tid = threadIdx.x;
  for (int u = tid; u < 768; u += 256) {
    int wl = u / 12, cv = u - wl * 12;
    int cc = c0 + cv * 8;
    float r[8] = {0.f, 0.f, 0.f, 0.f, 0.f, 0.f, 0.f, 0.f};
    for (int dy = 0; dy < 3; ++dy) {
      int sr = h + dy - 1;
      if (sr < 0 || sr >= 192) continue;
      for (int dx = 0; dx < 3; ++dx) {
        int sw = w0 + wl + dx - 1;
        if (sw < 0 || sw >= 192) continue;
        int tap = dy * 3 + dx;
        U16x8 v = *(const U16x8*)(kb + (size_t)(sr * 192 + sw) * 384 + cc);
        const float* dptr = dwt + tap * 384 + cc;
        #pragma unroll
        for (int j = 0; j < 8; ++j) r[j] += bf2f(v[j]) * dptr[j];
      }
    }
    if (cg < 2) {
      #pragma unroll
      for (int j = 0; j < 8; ++j) lt[(cv * 8 + j) * 72 + wl] = f2bf(r[j]);
    } else {
      U16x8 s;
      #pragma unroll
      for (int j = 0; j < 8; ++j) s[j] = f2bf(r[j]);
      *(U16x8*)(vnhwc + (size_t)b * IMG + (size_t)(h * 192 + w0 + wl) * NC + (cc - 192)) = s;
    }
  }
  if (cg < 2) {
    __syncthreads();
    for (int u = tid; u < 768; u += 256) {
      int cl = u >> 3, wo = u & 7;
      U16x8 s = *(const U16x8*)(lt + cl * 72 + wo * 8);
      *(U16x8*)(knchw + (size_t)b * IMG + (size_t)(c0 + cl) * NHW + h * 192 + w0 + wo * 8) = s;
    }
  }
}

// ------------------------------------- K3: q = 3x3 conv, m97-style implicit GEMM
// tile 128n x 192oc, BK=64 (27 chunks x 48 MFMA). global_load_lds staging into
// XOR-swizzled LDS: elem (row, oct) lives at row*128B + (oct^(row&7))*16B.
// grid (288, 4).
__global__ __launch_bounds__(256) void k_conv3x3(const unsigned short* xpad,
                                                 const unsigned short* wt9,
                                                 unsigned short* q) {
  __shared__ unsigned short As[8192];    // 128 rows x 64k = 16KB
  __shared__ unsigned short Bs[12288];   // 192 rows x 64k = 24KB
  int b = blockIdx.y, nt = blockIdx.x;
  int n0 = nt * 128;
  const unsigned short* xb = xpad + (size_t)b * PIMG;
  int tid = threadIdx.x, wave = tid >> 6, lane = tid & 63;
  int quad = lane >> 4, m = lane & 15;
  int ocs = (lane & 7) ^ ((lane >> 3) & 7);       // source oct for swizzled DMA
  int aoff[4];
  #pragma unroll
  for (int j = 0; j < 4; ++j) {                   // A rows this lane stages
    int row = (wave * 4 + j) * 8 + (lane >> 3);
    int n = n0 + row;
    int hh = n / 192, ww = n - hh * 192;
    aoff[j] = (hh * PP + ww) * 192 + ocs * 8;     // pad offset folded into tap term
  }
  int boff[6];
  #pragma unroll
  for (int j = 0; j < 6; ++j) {                   // B rows this lane stages
    int row = (wave * 6 + j) * 8 + (lane >> 3);
    boff[j] = row * 192 + ocs * 8;
  }
  int xa0 = ((quad) ^ (m & 7)) * 16;              // frag-read swizzle, ks=0
  int xa1 = ((4 + quad) ^ (m & 7)) * 16;          // ks=1
  F32x4 acc[8][3] = {};
  for (int tap = 0; tap < 9; ++tap) {
    int dy = tap / 3, dx = tap - dy * 3;
    int tapo = (dy * PP + dx) * 192;              // ph=h+dy, pw=w+dx (pad=1 built in)
    const unsigned short* wtb = wt9 + tap * 36864;
    for (int kc = 0; kc < 3; ++kc) {
      int ko = kc * 64;
      #pragma unroll
      for (int j = 0; j < 4; ++j)
        gl2lds16(xb + aoff[j] + tapo + ko, (char*)As + (wave * 4 + j) * 1024);
      #pragma unroll
      for (int j = 0; j < 6; ++j)
        gl2lds16(wtb + boff[j] + ko, (char*)Bs + (wave * 6 + j) * 1024);
      __syncthreads();
      #pragma unroll
      for (int ks = 0; ks < 2; ++ks) {
        int xa = ks ? xa1 : xa0;
        BF16x8 afr[8];
        #pragma unroll
        for (int rf = 0; rf < 8; ++rf)
          afr[rf] = *(const BF16x8*)((const char*)As + (rf * 16 + m) * 128 + xa);
        #pragma unroll
        for (int cf = 0; cf < 3; ++cf) {
          BF16x8 bfr = *(const BF16x8*)((const char*)Bs + (wave * 48 + cf * 16 + m) * 128 + xa);
          #pragma unroll
          for (int rf = 0; rf < 8; ++rf)
            acc[rf][cf] = __builtin_amdgcn_mfma_f32_16x16x32_bf16(afr[rf], bfr, acc[rf][cf], 0, 0, 0);
        }
      }
      __syncthreads();
    }
  }
  size_t qb = (size_t)b * IMG;
  #pragma unroll
  for (int rf = 0; rf < 8; ++rf)
    #pragma unroll
    for (int cf = 0; cf < 3; ++cf) {
      int oc = wave * 48 + cf * 16 + m;
      int nl = rf * 16 + quad * 4;
      U16x4 s;
      #pragma unroll
      for (int r = 0; r < 4; ++r) s[r] = f2bf(acc[rf][cf][r]);
      *(U16x4*)(q + qb + (size_t)oc * NHW + n0 + nl) = s;
    }
}

// --------------------------------------- K4a: G = [q;k][q;k]^T per (b, head)
__global__ __launch_bounds__(256) void k_gram(const unsigned short* q,
                                              const unsigned short* k, float* G) {
  __shared__ unsigned short Zs[64 * 72];
  int b = blockIdx.z, h = blockIdx.y, sp = blockIdx.x;
  const unsigned short* qb = q + (size_t)b * IMG + (size_t)h * 32 * NHW;
  const unsigned short* kb = k + (size_t)b * IMG + (size_t)h * 32 * NHW;
  int tid = threadIdx.x, wave = tid >> 6, lane = tid & 63;
  int quad = lane >> 4, m = lane & 15;
  F32x4 acc[4] = {};
  for (int it = 0; it < 18; ++it) {
    int nb = sp * 1152 + it * 64;
    for (int u = tid; u < 512; u += 256) {
      int row = u >> 3, oct = u & 7;
      const unsigned short* src = (row < 32) ? (qb + (size_t)row * NHW)
                                             : (kb + (size_t)(row - 32) * NHW);
      U16x8 v = *(const U16x8*)(src + nb + oct * 8);
      *(U16x8*)(Zs + row * 72 + oct * 8) = v;
    }
    __syncthreads();
    #pragma unroll
    for (int ks = 0; ks < 2; ++ks) {
      BF16x8 afr = *(const BF16x8*)(Zs + (wave * 16 + m) * 72 + ks * 32 + quad * 8);
      #pragma unroll
      for (int cg = 0; cg < 4; ++cg) {
        BF16x8 bfr = *(const BF16x8*)(Zs + (cg * 16 + m) * 72 + ks * 32 + quad * 8);
        acc[cg] = __builtin_amdgcn_mfma_f32_16x16x32_bf16(afr, bfr, acc[cg], 0, 0, 0);
      }
    }
    __syncthreads();
  }
  float* Gb = G + (size_t)(b * 6 + h) * 4096;
  #pragma unroll
  for (int cg = 0; cg < 4; ++cg) {
    int s = cg * 16 + m;
    #pragma unroll
    for (int r = 0; r < 4; ++r) {
      int row = wave * 16 + quad * 4 + r;
      atomicAdd(Gb + row * 64 + s, acc[cg][r]);
    }
  }
}

// ------------------- K4b: softmax + M_b = proj_w @ blockdiag(attn). grid(24)
__global__ __launch_bounds__(256) void k_attn(const float* G, const float* temp6,
                                              const unsigned short* pjw,
                                              unsigned short* M) {
  __shared__ float attn[32][33];
  int bh = blockIdx.x;
  int b = bh / 6, h = bh - b * 6;
  const float* Gb = G + (size_t)bh * 4096;
  int tid = threadIdx.x;
  float temp = temp6[h];
  if (tid < 32) {
    int c = tid;
    float qn = sqrtf(fmaxf(Gb[c * 64 + c], 0.f));
    qn = fmaxf(qn, 1e-12f);
    float s[32];
    float mx = -1e30f;
    for (int d = 0; d < 32; ++d) {
      float kn = sqrtf(fmaxf(Gb[(32 + d) * 64 + 32 + d], 0.f));
      kn = fmaxf(kn, 1e-12f);
      float v = Gb[c * 64 + 32 + d] / (qn * kn) * temp;
      s[d] = v;
      mx = fmaxf(mx, v);
    }
    float sum = 0.f;
    for (int d = 0; d < 32; ++d) { float e = __expf(s[d] - mx); s[d] = e; sum += e; }
    float inv = 1.f / sum;
    for (int d = 0; d < 32; ++d) attn[c][d] = s[d] * inv;
  }
  __syncthreads();
  for (int u = tid; u < 6144; u += 256) {
    int oc = u >> 5, d = u & 31;
    float sum = 0.f;
    #pragma unroll
    for (int c = 0; c < 32; ++c)
      sum += bf2f(pjw[oc * 192 + h * 32 + c]) * attn[c][d];
    M[(size_t)b * 36864 + oc * 192 + h * 32 + d] = f2bf(sum);
  }
}

// ------------------------------- K5: out = M_b @ v (fused attn@v + proj 1x1)
__global__ __launch_bounds__(256) void k_out(const unsigned short* v,
                                             const unsigned short* M,
                                             const int* flagp, void* out) {
  __shared__ unsigned short As[64 * 40];
  __shared__ unsigned short Bs[192 * 40];
  int b = blockIdx.y, nt = blockIdx.x;
  int n0 = nt * 64;
  const unsigned short* vb = v + (size_t)b * IMG;
  const unsigned short* Mb = M + (size_t)b * 36864;
  int tid = threadIdx.x, wave = tid >> 6, lane = tid & 63;
  int quad = lane >> 4, m = lane & 15;
  F32x4 acc[4][3] = {};
  for (int kc = 0; kc < 6; ++kc) {
    int k0 = kc * 32;
    {
      int rl = tid >> 2, oct = tid & 3;
      U16x8 vv = *(const U16x8*)(vb + (size_t)(n0 + rl) * NC + k0 + oct * 8);
      *(U16x8*)(As + rl * 40 + oct * 8) = vv;
    }
    for (int u = tid; u < 768; u += 256) {
      int row = u >> 2, oct = u & 3;
      U16x8 vv = *(const U16x8*)(Mb + row * 192 + k0 + oct * 8);
      *(U16x8*)(Bs + row * 40 + oct * 8) = vv;
    }
    __syncthreads();
    BF16x8 afr[4];
    #pragma unroll
    for (int rf = 0; rf < 4; ++rf)
      afr[rf] = *(const BF16x8*)(As + (rf * 16 + m) * 40 + quad * 8);
    #pragma unroll
    for (int cf = 0; cf < 3; ++cf) {
      BF16x8 bfr = *(const BF16x8*)(Bs + (wave * 48 + cf * 16 + m) * 40 + quad * 8);
      #pragma unroll
      for (int rf = 0; rf < 4; ++rf)
        acc[rf][cf] = __builtin_amdgcn_mfma_f32_16x16x32_bf16(afr[rf], bfr, acc[rf][cf], 0, 0, 0);
    }
    __syncthreads();
  }
  int flag = *flagp;
  #pragma unroll
  for (int rf = 0; rf < 4; ++rf)
    #pragma unroll
    for (int cf = 0; cf < 3; ++cf) {
      int oc = wave * 48 + cf * 16 + m;
      int nl = rf * 16 + quad * 4;
      size_t off = (size_t)b * IMG + (size_t)oc * NHW + n0 + nl;
      if (flag) {
        U16x4 s;
        #pragma unroll
        for (int r = 0; r < 4; ++r) s[r] = f2bf(acc[rf][cf][r]);
        *(U16x4*)((unsigned short*)out + off) = s;
      } else {
        F32x4 s;
        #pragma unroll
        for (int r = 0; r < 4; ++r) s[r] = acc[rf][cf][r];
        *(F32x4*)((float*)out + off) = s;
      }
    }
}

extern "C" void kernel_launch(void* const* d_in, const int* in_sizes, int n_in,
                              void* d_out, int out_size, void* d_ws, size_t ws_size,
                              hipStream_t stream) {
  (void)in_sizes; (void)n_in; (void)out_size; (void)ws_size;
  char* p = (char*)d_ws;
  int*            flag  = (int*)p;
  float*          temp6 = (float*)(p + 16);
  unsigned short* wt9   = (unsigned short*)(p + 64);         //   663,552 B
  unsigned short* kvwt  = (unsigned short*)(p + 663616);     //   147,456 B
  float*          dwt   = (float*)(p + 811072);              //    13,824 B
  unsigned short* pjwt  = (unsigned short*)(p + 824896);     //    73,728 B
  unsigned short* xpad  = (unsigned short*)(p + 898624);     // 57,808,896 B (padded x NHWC)
  unsigned short* yt    = (unsigned short*)(p + 58707520);   // 56,623,104 B (y NHWC; later k NCHW)
  unsigned short* kv0   = (unsigned short*)(p + 115330624);  // 113,246,208 B (kv NHWC; later q NCHW)
  unsigned short* vv    = (unsigned short*)(p + 228576832);  // 56,623,104 B (v NHWC)  -> end 285,199,936
  float*          G     = (float*)xpad;                      // alias: xpad dead after conv3x3
  unsigned short* M     = (unsigned short*)((char*)xpad + 393216);
  unsigned short* kq    = yt;   // k NCHW aliases yt (dead after conv1x1)
  unsigned short* q     = kv0;  // q NCHW aliases kv0 (dead after dw)

  k_detect<<<1, 64, 0, stream>>>(d_in[6], flag, temp6);
  k_prep<<<512, 256, 0, stream>>>(d_in[2], d_in[3], d_in[5], d_in[4],
                                  flag, wt9, kvwt, pjwt, dwt);
  k_halo<<<4, 256, 0, stream>>>(xpad);
  k_transpose<<<dim3(576, 24, 2), 256, 0, stream>>>(d_in[0], d_in[1], flag, xpad, yt);
  k_conv1x1<<<dim3(576, 2, 4), 256, 0, stream>>>(yt, kvwt, kv0);
  k_dw<<<dim3(576, 4, 4), 256, 0, stream>>>(kv0, dwt, kq, vv);
  k_conv3x3<<<dim3(288, 4), 256, 0, stream>>>(xpad, wt9, q);
  hipMemsetAsync(G, 0, (size_t)24 * 4096 * 4, stream);       // after conv3x3: G aliases xpad
  k_gram<<<dim3(32, 6, 4), 256, 0, stream>>>(q, kq, G);
  k_attn<<<24, 256, 0, stream>>>(G, temp6, pjwt, M);
  k_out<<<dim3(576, 4), 256, 0, stream>>>(vv, M, flag, d_out);
}